// Round 6
// baseline (71.939 us; speedup 1.0000x reference)
//
#include <hip/hip_runtime.h>
#include <hip/hip_bf16.h>

#define EPS 1e-7f

typedef __attribute__((ext_vector_type(8))) short short8;
typedef __attribute__((ext_vector_type(4))) float f32x4;

// pack two floats to two bf16 (RNE) in one uint (low = first)
__device__ __forceinline__ unsigned pk(float a, float b) {
    __hip_bfloat162 h2 = __float22bfloat162_rn(make_float2(a, b));
    unsigned r; __builtin_memcpy(&r, &h2, 4); return r;
}

__device__ __forceinline__ short8 mk8(float4 f0, float4 f1) {
    uint4 u;
    u.x = pk(f0.x, f0.y); u.y = pk(f0.z, f0.w);
    u.z = pk(f1.x, f1.y); u.w = pk(f1.z, f1.w);
    short8 r; __builtin_memcpy(&r, &u, 16); return r;
}

// ---------------------------------------------------------------------------
// K0: A(fp32,[256][256]) -> Aswz(bf16, B-fragment order)  +  Ac / bmAc (fp32)
// fragment linearization: u = (T*8 + s)*64 + l  holds
//   A[16*T + (l&15)][32*s + 8*(l>>4) + i], i=0..7   (16B per lane)
// ---------------------------------------------------------------------------
__global__ __launch_bounds__(256)
void prep_kernel(const float* __restrict__ A, const float* __restrict__ bb,
                 const float* __restrict__ c, short* __restrict__ Aswz,
                 float* __restrict__ Ac, float* __restrict__ bmAc)
{
    const int blk = blockIdx.x;
    const int t = threadIdx.x;
    if (blk < 32) {
        const int u = blk * 256 + t;
        const int l = u & 63;
        const int s = (u >> 6) & 7;
        const int T = u >> 9;
        const int row = T * 16 + (l & 15);
        const int n0 = s * 32 + ((l >> 4) & 3) * 8;
        const float4* ap = (const float4*)(A + (size_t)row * 256 + n0);
        float4 f0 = ap[0];
        float4 f1 = ap[1];
        uint4 v;
        v.x = pk(f0.x, f0.y); v.y = pk(f0.z, f0.w);
        v.z = pk(f1.x, f1.y); v.w = pk(f1.z, f1.w);
        *(uint4*)(Aswz + (size_t)u * 8) = v;
    } else {
        // 64 blocks x 4 waves: one A-row dot c per wave (fp32 exact)
        const int g = blk - 32;
        const int w = t >> 6;
        const int lane = t & 63;
        const int row = g * 4 + w;
        const float4* a4 = (const float4*)(A + (size_t)row * 256);
        const float4* c4 = (const float4*)c;
        float4 av = a4[lane], cv = c4[lane];
        float p = av.x * cv.x + av.y * cv.y + av.z * cv.z + av.w * cv.w;
        #pragma unroll
        for (int off = 1; off < 64; off <<= 1) p += __shfl_xor(p, off);
        if (lane == 0) {
            Ac[row] = p;
            bmAc[row] = bb[row] - p;
        }
    }
}

// ---------------------------------------------------------------------------
// K1: block = 16 batch rows x all 256 m; 1024 threads (16 waves, 4/SIMD).
//   wave w owns m-tile w (m = 16w + lr). No LDS staging:
//   y-frags straight from global (L2-hot), B-frags coalesced bf16 from Aswz.
//   dot = acc(A*y) - Ac  (fp32 correction), cand/min -> alpha -> z.
// ---------------------------------------------------------------------------
__global__ __launch_bounds__(1024, 4)
void gemm_kernel(const float* __restrict__ y, const float* __restrict__ c,
                 const short* __restrict__ Aswz, const float* __restrict__ Ac,
                 const float* __restrict__ bmAc, float* __restrict__ z)
{
    __shared__ float red[16][16];
    __shared__ float alphas[16];

    const int t    = threadIdx.x;
    const int w    = t >> 6;      // wave = m-tile index
    const int lane = t & 63;
    const int lr   = lane & 15;   // A-frag row (batch) / B-frag col (m)
    const int lg   = lane >> 4;   // k-group
    const int b0   = blockIdx.x * 16;

    f32x4 acc = {0.f, 0.f, 0.f, 0.f};

    const float4* yp = (const float4*)(y + (size_t)(b0 + lr) * 256) + lg * 2;
    const short8* bp = (const short8*)Aswz + (size_t)(w * 8) * 64 + lane;

    #pragma unroll
    for (int s = 0; s < 8; ++s) {
        float4 f0 = yp[8 * s];      // y[b0+lr][32s+8lg .. +3]
        float4 f1 = yp[8 * s + 1];  // y[b0+lr][32s+8lg+4 .. +7]
        short8 af = mk8(f0, f1);
        short8 bf = bp[s * 64];     // coalesced 16B/lane
        acc = __builtin_amdgcn_mfma_f32_16x16x32_bf16(af, bf, acc, 0, 0, 0);
    }

    // cand + min over this wave's 16 m (C/D: col m = 16w+lr, batch row = 4lg+q)
    const int m = w * 16 + lr;
    const float Acm = Ac[m];
    const float bmm = bmAc[m];

    float cmin[4];
    #pragma unroll
    for (int q = 0; q < 4; ++q) {
        float d  = acc[q] - Acm;          // A·(y-c) with fp32 Ac correction
        float ip = bmm / (d + EPS);
        cmin[q] = (ip > 1.f || ip < 0.f) ? 2.f : ip;
    }
    #pragma unroll
    for (int q = 0; q < 4; ++q) {
        float v = cmin[q];
        v = fminf(v, __shfl_xor(v, 1));
        v = fminf(v, __shfl_xor(v, 2));
        v = fminf(v, __shfl_xor(v, 4));
        v = fminf(v, __shfl_xor(v, 8));
        cmin[q] = v;
    }
    if (lr == 0) {
        #pragma unroll
        for (int q = 0; q < 4; ++q) red[w][lg * 4 + q] = cmin[q];
    }
    __syncthreads();

    if (t < 16) {
        float a = red[0][t];
        #pragma unroll
        for (int i = 1; i < 16; ++i) a = fminf(a, red[i][t]);
        alphas[t] = fminf(a, 1.0f);   // alpha > 1 -> 1
    }
    __syncthreads();

    // epilogue: z = c + alpha*(y - c); 1024 threads = 16 rows x 64 float4,
    // fully coalesced; y re-read is L2-hot.
    {
        const int row  = t >> 6;
        const int col4 = t & 63;
        const float4* y4  = (const float4*)y;
        const float4* c4g = (const float4*)c;
        float4* z4 = (float4*)z;
        float al  = alphas[row];
        float4 yv = y4[(size_t)(b0 + row) * 64 + col4];
        float4 cv = c4g[col4];
        float4 o;
        o.x = fmaf(al, yv.x - cv.x, cv.x);
        o.y = fmaf(al, yv.y - cv.y, cv.y);
        o.z = fmaf(al, yv.z - cv.z, cv.z);
        o.w = fmaf(al, yv.w - cv.w, cv.w);
        z4[(size_t)(b0 + row) * 64 + col4] = o;
    }
}

extern "C" void kernel_launch(void* const* d_in, const int* in_sizes, int n_in,
                              void* d_out, int out_size, void* d_ws, size_t ws_size,
                              hipStream_t stream) {
    const float* y = (const float*)d_in[0];
    const float* A = (const float*)d_in[1];
    const float* b = (const float*)d_in[2];
    const float* c = (const float*)d_in[3];
    float* z = (float*)d_out;

    short* Aswz  = (short*)d_ws;                       // 128 KB
    float* Acp   = (float*)((char*)d_ws + 131072);     // 1 KB
    float* bmAcp = Acp + 256;                          // 1 KB

    const int B = in_sizes[0] / 256;                   // 4096

    prep_kernel<<<96, 256, 0, stream>>>(A, b, c, Aswz, Acp, bmAcp);
    gemm_kernel<<<B / 16, 1024, 0, stream>>>(y, c, Aswz, Acp, bmAcp, z);
}